// Round 11
// baseline (167.707 us; speedup 1.0000x reference)
//
#include <hip/hip_runtime.h>
#include <hip/hip_fp16.h>
#include <stdint.h>

#define BATCH 4096
#define N_IN  512
#define H1    1536
#define H2    1536
#define N_OUT 512
#define FAN   32
#define E0 (H1 * FAN)
#define E1 (H2 * FAN)
#define E2 (N_OUT * FAN)
#define K1 N_IN               // 512
#define K2 (N_IN + H1)        // 2048
#define K3 (N_IN + H1 + H2)   // 3584

// nvT: activations batch-major [4096][3584] fp16. cols 0..511 = x,
// 512..2047 = h1, 2048..3583 = h2. K-contiguous: both GEMM operands K-major.
#define NVSTRIDE 3584
#define NVBYTES  ((size_t)BATCH * NVSTRIDE * 2)         // 29,360,128
#define W0BYTES  ((size_t)H1 * K1 * 2)                  //  1,572,864
#define W1BYTES  ((size_t)H2 * K2 * 2)                  //  6,291,456
#define W2BYTES  ((size_t)N_OUT * K3 * 2)               //  3,670,016
// W region: [W0 | W1] = 7,864,320 bytes; W2 (3.67 MB) overlays it after GEMM2.
// Total ws = 37,224,448 (< 37,238,784 proven in R0)
#define WZU4  ((W0BYTES + W1BYTES) / 16)                // 491,520 uint4

typedef _Float16 f16x8 __attribute__((ext_vector_type(8)));
typedef float    f32x4 __attribute__((ext_vector_type(4)));

#define GLL(SRC, DST)                                                        \
    __builtin_amdgcn_global_load_lds(                                        \
        (const __attribute__((address_space(1))) void*)(const void*)(SRC),   \
        (__attribute__((address_space(3))) void*)(void*)(DST), 16, 0, 0)

// ---------- fused: x [B][512] fp32 -> nvT fp16  +  zero W0/W1 region ----------
// Blocks 0..1023: convert; blocks 1024..2943: memset. Independent writes; the
// scatter-fill runs in the NEXT dispatch, so no ordering hazard.
__global__ __launch_bounds__(256) void k_xcvt_zero(const float* __restrict__ x,
                                                   __half* __restrict__ nvT,
                                                   uint4* __restrict__ Wz) {
    const int b = blockIdx.x;
    if (b < 1024) {
        const int t  = b * 256 + threadIdx.x;   // 0 .. 4096*64-1
        const int n  = t >> 6;
        const int c8 = t & 63;
        const float4 f0 = *(const float4*)(x + (size_t)n * N_IN + c8 * 8);
        const float4 f1 = *(const float4*)(x + (size_t)n * N_IN + c8 * 8 + 4);
        const __half2 a = __floats2half2_rn(f0.x, f0.y);
        const __half2 bb = __floats2half2_rn(f0.z, f0.w);
        const __half2 c = __floats2half2_rn(f1.x, f1.y);
        const __half2 d = __floats2half2_rn(f1.z, f1.w);
        uint4 u;
        u.x = *(const uint32_t*)&a; u.y = *(const uint32_t*)&bb;
        u.z = *(const uint32_t*)&c; u.w = *(const uint32_t*)&d;
        *(uint4*)(nvT + (size_t)n * NVSTRIDE + c8 * 8) = u;
    } else {
        const int i = (b - 1024) * 256 + threadIdx.x;
        if (i < WZU4) Wz[i] = make_uint4(0, 0, 0, 0);
    }
}

// ---------- fp16 scatter-add (CAS on containing dword; duplicates accumulate) ----------
__device__ __forceinline__ void atomic_add_half(__half* addr, float val) {
    uint32_t* base = (uint32_t*)((size_t)addr & ~(size_t)3);
    const bool hi  = ((size_t)addr & 2) != 0;
    uint32_t old = *base, assumed;
    do {
        assumed = old;
        __half2 h2 = *(__half2*)&assumed;
        float f = (hi ? __high2float(h2) : __low2float(h2)) + val;
        __half2 nh = hi ? __halves2half2(__low2half(h2), __float2half_rn(f))
                        : __halves2half2(__float2half_rn(f), __high2half(h2));
        old = atomicCAS(base, assumed, *(uint32_t*)&nh);
    } while (old != assumed);
}

__global__ __launch_bounds__(256) void k_wfill01(
        const int* __restrict__ s0, const int* __restrict__ d0, const float* __restrict__ w0,
        const int* __restrict__ s1, const int* __restrict__ d1, const float* __restrict__ w1,
        __half* __restrict__ W0d, __half* __restrict__ W1d) {
    const int e = blockIdx.x * 256 + threadIdx.x;
    if (e < E0)  atomic_add_half(W0d + (size_t)d0[e] * K1 + s0[e], w0[e]);
    else { const int i = e - E0; atomic_add_half(W1d + (size_t)d1[i] * K2 + s1[i], w1[i]); }
}

__global__ __launch_bounds__(256) void k_wfill(const int* __restrict__ src,
                                               const int* __restrict__ dst,
                                               const float* __restrict__ w,
                                               __half* __restrict__ Wd, const int K) {
    const int e = blockIdx.x * 256 + threadIdx.x;
    atomic_add_half(Wd + (size_t)dst[e] * K + src[e], w[e]);
}

// ---------- GEMM levels 1/2: BM=96, BN=128, 512 thr (8 waves), quad-buffer ----
// R10's gemm3 structure (the one that improved): depth-2 prefetch, ONE barrier
// per step {STAGE(t+2); counted vmcnt; barrier; compute(t&3)}. Overwrite target
// (t+2)&3 was read at compute(t-2), fenced by barrier(t-1) — safe without a
// second barrier. Role-split staging: waves 0-3 stage A (3 loads each), waves
// 4-7 stage B (4 each); per-role counted vmcnt keeps 2 tiles of loads in
// flight, never draining to 0 mid-loop (m218 lever). LDS 114.7KB -> 1 blk/CU,
// 8 waves = 2/SIMD (same wave count as R10's 2x4-wave blocks, better schedule).
__global__ __launch_bounds__(512, 2)
void k_gemm96(const __half* __restrict__ A,    // [M][K] dense W, row stride K
              const __half* __restrict__ Bt,   // nvT, row stride NVSTRIDE
              __half* __restrict__ Ch,         // nvT + col0
              const int K) {
    __shared__ __half lA[4][96 * 64];
    __shared__ __half lB[4][128 * 64];
    const int tid  = threadIdx.x;
    const int lane = tid & 63;
    const int wv   = tid >> 6;                  // 0..7
    const int wr   = wv >> 2, wc = wv & 3;      // 2 x 4 wave grid
    const int m0   = blockIdx.y * 96;
    const int n0   = blockIdx.x * 128;
    const int lrow = lane >> 3;
    const int lchk = lane & 7;

    f32x4 acc[3][2] = {};

#define STG96(BUF, KT) {                                                     \
    if (wv < 4) {                                                            \
        _Pragma("unroll")                                                    \
        for (int i = 0; i < 3; ++i) {                                        \
            const int g   = wv * 3 + i;        /* 0..11: A 8-row groups */   \
            const int row = g * 8 + lrow;                                    \
            const int sc  = lchk ^ (row & 7);                                \
            GLL(A + (size_t)(m0 + row) * K + (KT) + sc * 8,                  \
                lA[BUF] + g * 512);                                          \
        }                                                                    \
    } else {                                                                 \
        _Pragma("unroll")                                                    \
        for (int i = 0; i < 4; ++i) {                                        \
            const int g   = (wv - 4) * 4 + i;  /* 0..15: B 8-row groups */   \
            const int row = g * 8 + lrow;                                    \
            const int sc  = lchk ^ (row & 7);                                \
            GLL(Bt + (size_t)(n0 + row) * NVSTRIDE + (KT) + sc * 8,          \
                lB[BUF] + g * 512);                                          \
        }                                                                    \
    }                                                                        \
}

    const int NT = K >> 6;
    STG96(0, 0)
    STG96(1, 64)
    for (int t = 0; t < NT; ++t) {
        if (t + 2 < NT) {
            STG96((t + 2) & 3, (t + 2) << 6)
            if (wv < 4) asm volatile("s_waitcnt vmcnt(6)" ::: "memory");
            else        asm volatile("s_waitcnt vmcnt(8)" ::: "memory");
        } else if (t + 1 < NT) {
            if (wv < 4) asm volatile("s_waitcnt vmcnt(3)" ::: "memory");
            else        asm volatile("s_waitcnt vmcnt(4)" ::: "memory");
        } else {
            asm volatile("s_waitcnt vmcnt(0)" ::: "memory");
        }
        __builtin_amdgcn_sched_barrier(0);
        __builtin_amdgcn_s_barrier();           // all waves' tile-t data in LDS
        __builtin_amdgcn_sched_barrier(0);
        const __half* bA = lA[t & 3];
        const __half* bB = lB[t & 3];
#pragma unroll
        for (int kk = 0; kk < 2; ++kk) {
            f16x8 af[3], bf[2];
#pragma unroll
            for (int fm = 0; fm < 3; ++fm) {
                const int row = wr * 48 + fm * 16 + (lane & 15);
                const int ch  = (kk * 4 + (lane >> 4)) ^ (row & 7);
                af[fm] = *(const f16x8*)(bA + row * 64 + ch * 8);
            }
#pragma unroll
            for (int fn = 0; fn < 2; ++fn) {
                const int row = wc * 32 + fn * 16 + (lane & 15);
                const int ch  = (kk * 4 + (lane >> 4)) ^ (row & 7);
                bf[fn] = *(const f16x8*)(bB + row * 64 + ch * 8);
            }
#pragma unroll
            for (int fm = 0; fm < 3; ++fm)
#pragma unroll
                for (int fn = 0; fn < 2; ++fn)
                    acc[fm][fn] = __builtin_amdgcn_mfma_f32_16x16x32_f16(
                        af[fm], bf[fn], acc[fm][fn], 0, 0, 0);
        }
    }
#undef STG96

    const int cm = (lane >> 4) << 2;
    const int cn = lane & 15;
#pragma unroll
    for (int fm = 0; fm < 3; ++fm)
#pragma unroll
        for (int fn = 0; fn < 2; ++fn) {
            const f32x4 v = acc[fm][fn];
            const __half2 p0 = __floats2half2_rn(fmaxf(v[0], 0.f), fmaxf(v[1], 0.f));
            const __half2 p1 = __floats2half2_rn(fmaxf(v[2], 0.f), fmaxf(v[3], 0.f));
            const int mm = m0 + wr * 48 + fm * 16 + cm;
            const int nn = n0 + wc * 32 + fn * 16 + cn;
            uint2 u; u.x = *(const uint32_t*)&p0; u.y = *(const uint32_t*)&p1;
            *(uint2*)(Ch + (size_t)nn * NVSTRIDE + mm) = u;
        }
}

// ---------- GEMM level 3 (byte-identical to R10: passed, improved) ----------
__global__ __launch_bounds__(512, 2)
void k_gemm3(const __half* __restrict__ A,     // [512][3584] dense W2
             const __half* __restrict__ Bt,    // nvT
             float* __restrict__ Cf) {         // d_out [4096][512]
    __shared__ __half lA[4][64 * 64];
    __shared__ __half lB[4][128 * 64];
    const int tid  = threadIdx.x;
    const int lane = tid & 63;
    const int wv   = tid >> 6;                  // 0..7
    const int wr   = wv >> 2, wc = wv & 3;      // 2 x 4 wave grid
    const int m0   = blockIdx.y * 64;
    const int n0   = blockIdx.x * 128;
    const int lrow = lane >> 3;
    const int lchk = lane & 7;
    const int K = K3;

    f32x4 acc[2][2] = {};

#define STAGE3(BUF, KT) {                                                    \
    _Pragma("unroll")                                                        \
    for (int i = 0; i < 3; ++i) {                                            \
        const int L = wv * 3 + i;               /* 0..23, wave-uniform */    \
        if (L < 8) {                                                         \
            const int row = L * 8 + lrow;                                    \
            const int sc  = lchk ^ (row & 7);                                \
            GLL(A + (size_t)(m0 + row) * K + (KT) + sc * 8,                  \
                lA[BUF] + L * 512);                                          \
        } else {                                                             \
            const int row = (L - 8) * 8 + lrow;                              \
            const int sc  = lchk ^ (row & 7);                                \
            GLL(Bt + (size_t)(n0 + row) * NVSTRIDE + (KT) + sc * 8,          \
                lB[BUF] + (L - 8) * 512);                                    \
        }                                                                    \
    }                                                                        \
}

    const int NT = K >> 6;   // 56
    STAGE3(0, 0)
    STAGE3(1, 64)
    for (int t = 0; t < NT; ++t) {
        if (t + 2 < NT) {
            STAGE3((t + 2) & 3, (t + 2) << 6)
            asm volatile("s_waitcnt vmcnt(6)" ::: "memory");   // t landed; t+1,t+2 fly
        } else if (t + 1 < NT) {
            asm volatile("s_waitcnt vmcnt(3)" ::: "memory");
        } else {
            asm volatile("s_waitcnt vmcnt(0)" ::: "memory");
        }
        __builtin_amdgcn_sched_barrier(0);
        __builtin_amdgcn_s_barrier();
        __builtin_amdgcn_sched_barrier(0);
        const __half* bA = lA[t & 3];
        const __half* bB = lB[t & 3];
#pragma unroll
        for (int kk = 0; kk < 2; ++kk) {
            f16x8 af[2], bf[2];
#pragma unroll
            for (int fm = 0; fm < 2; ++fm) {
                const int row = wr * 32 + fm * 16 + (lane & 15);
                const int ch  = (kk * 4 + (lane >> 4)) ^ (row & 7);
                af[fm] = *(const f16x8*)(bA + row * 64 + ch * 8);
            }
#pragma unroll
            for (int fn = 0; fn < 2; ++fn) {
                const int row = wc * 32 + fn * 16 + (lane & 15);
                const int ch  = (kk * 4 + (lane >> 4)) ^ (row & 7);
                bf[fn] = *(const f16x8*)(bB + row * 64 + ch * 8);
            }
#pragma unroll
            for (int fm = 0; fm < 2; ++fm)
#pragma unroll
                for (int fn = 0; fn < 2; ++fn)
                    acc[fm][fn] = __builtin_amdgcn_mfma_f32_16x16x32_f16(
                        af[fm], bf[fn], acc[fm][fn], 0, 0, 0);
        }
    }
#undef STAGE3

    const int cm = (lane >> 4) << 2;
    const int cn = lane & 15;
#pragma unroll
    for (int fm = 0; fm < 2; ++fm)
#pragma unroll
        for (int fn = 0; fn < 2; ++fn) {
            const f32x4 v = acc[fm][fn];
            float4 o;
            o.x = fmaxf(v[0], 0.f); o.y = fmaxf(v[1], 0.f);
            o.z = fmaxf(v[2], 0.f); o.w = fmaxf(v[3], 0.f);
            const int mm = m0 + wr * 32 + fm * 16 + cm;
            const int nn = n0 + wc * 32 + fn * 16 + cn;
            *(float4*)(Cf + (size_t)nn * N_OUT + mm) = o;
        }
}

extern "C" void kernel_launch(void* const* d_in, const int* in_sizes, int n_in,
                              void* d_out, int out_size, void* d_ws, size_t ws_size,
                              hipStream_t stream) {
    const float* x  = (const float*)d_in[0];
    const int* s0   = (const int*)d_in[1];
    const int* dd0  = (const int*)d_in[2];
    const float* w0 = (const float*)d_in[3];
    const int* s1   = (const int*)d_in[4];
    const int* dd1  = (const int*)d_in[5];
    const float* w1 = (const float*)d_in[6];
    const int* s2   = (const int*)d_in[7];
    const int* dd2  = (const int*)d_in[8];
    const float* w2 = (const float*)d_in[9];

    char*   ws  = (char*)d_ws;
    __half* nvT = (__half*)ws;
    __half* W0p = (__half*)(ws + NVBYTES);            // region start
    __half* W1p = (__half*)(ws + NVBYTES + W0BYTES);
    __half* W2p = W0p;                                // overlays W0/W1 after GEMM2
    float*  out = (float*)d_out;

    // fused: x -> nvT cols 0..511  +  zero W0/W1 region
    k_xcvt_zero<<<1024 + (WZU4 + 255) / 256, 256, 0, stream>>>(x, nvT, (uint4*)W0p);

    // W0 + W1 build, then levels 1/2
    k_wfill01<<<(E0 + E1) / 256, 256, 0, stream>>>(s0, dd0, w0, s1, dd1, w1, W0p, W1p);
    k_gemm96<<<dim3(BATCH / 128, H1 / 96), 512, 0, stream>>>(W0p, nvT, nvT + N_IN, K1);
    k_gemm96<<<dim3(BATCH / 128, H2 / 96), 512, 0, stream>>>(W1p, nvT, nvT + K2, K2);

    // W2 build (overlaying the now-dead W0/W1), then level 3 -> d_out
    hipMemsetAsync(W2p, 0, W2BYTES, stream);
    k_wfill<<<E2 / 256, 256, 0, stream>>>(s2, dd2, w2, W2p, K3);
    k_gemm3<<<dim3(BATCH / 128, N_OUT / 64), 512, 0, stream>>>(W2p, nvT, out);
}

// Round 12
// 156.947 us; speedup vs baseline: 1.0686x; 1.0686x over previous
//
#include <hip/hip_runtime.h>
#include <hip/hip_fp16.h>
#include <stdint.h>

#define BATCH 4096
#define N_IN  512
#define H1    1536
#define H2    1536
#define N_OUT 512
#define FAN   32
#define E0 (H1 * FAN)
#define E1 (H2 * FAN)
#define E2 (N_OUT * FAN)
#define ETOT (E0 + E1 + E2)
#define K1 N_IN               // 512
#define K2 (N_IN + H1)        // 2048
#define K3 (N_IN + H1 + H2)   // 3584

// nvT: activations batch-major [4096][3584] fp16. cols 0..511 = x,
// 512..2047 = h1, 2048..3583 = h2. K-contiguous: both GEMM operands K-major.
#define NVSTRIDE 3584
#define NVBYTES  ((size_t)BATCH * NVSTRIDE * 2)         // 29,360,128
#define W0BYTES  ((size_t)H1 * K1 * 2)                  //  1,572,864
#define W1BYTES  ((size_t)H2 * K2 * 2)                  //  6,291,456
#define W2BYTES  ((size_t)N_OUT * K3 * 2)               //  3,670,016
// Fused path (ws >= 40,894,464): separate W2 -> 5 dispatches.
// Fallback  (proven 37,224,448): W2 overlays W0/W1 -> exact R10 7-dispatch path.
#define WZ01U4   ((W0BYTES + W1BYTES) / 16)             // 491,520 uint4
#define WZALLU4  ((W0BYTES + W1BYTES + W2BYTES) / 16)   // 720,896 uint4

typedef _Float16 f16x8 __attribute__((ext_vector_type(8)));
typedef float    f32x4 __attribute__((ext_vector_type(4)));

#define GLL(SRC, DST)                                                        \
    __builtin_amdgcn_global_load_lds(                                        \
        (const __attribute__((address_space(1))) void*)(const void*)(SRC),   \
        (__attribute__((address_space(3))) void*)(void*)(DST), 16, 0, 0)

// ---------- fused: x [B][512] fp32 -> nvT fp16  +  zero W region(s) ----------
// Blocks 0..1023 convert; blocks >=1024 zero nzu4 uint4s at Wz. The scatter-fill
// runs in the NEXT dispatch, so no ordering hazard.
__global__ __launch_bounds__(256) void k_xcvt_zero(const float* __restrict__ x,
                                                   __half* __restrict__ nvT,
                                                   uint4* __restrict__ Wz,
                                                   const int nzu4) {
    const int b = blockIdx.x;
    if (b < 1024) {
        const int t  = b * 256 + threadIdx.x;   // 0 .. 4096*64-1
        const int n  = t >> 6;
        const int c8 = t & 63;
        const float4 f0 = *(const float4*)(x + (size_t)n * N_IN + c8 * 8);
        const float4 f1 = *(const float4*)(x + (size_t)n * N_IN + c8 * 8 + 4);
        const __half2 a = __floats2half2_rn(f0.x, f0.y);
        const __half2 bb = __floats2half2_rn(f0.z, f0.w);
        const __half2 c = __floats2half2_rn(f1.x, f1.y);
        const __half2 d = __floats2half2_rn(f1.z, f1.w);
        uint4 u;
        u.x = *(const uint32_t*)&a; u.y = *(const uint32_t*)&bb;
        u.z = *(const uint32_t*)&c; u.w = *(const uint32_t*)&d;
        *(uint4*)(nvT + (size_t)n * NVSTRIDE + c8 * 8) = u;
    } else {
        const int i = (b - 1024) * 256 + threadIdx.x;
        if (i < nzu4) Wz[i] = make_uint4(0, 0, 0, 0);
    }
}

// ---------- fp16 scatter-add (CAS on containing dword; duplicates accumulate) ----------
__device__ __forceinline__ void atomic_add_half(__half* addr, float val) {
    uint32_t* base = (uint32_t*)((size_t)addr & ~(size_t)3);
    const bool hi  = ((size_t)addr & 2) != 0;
    uint32_t old = *base, assumed;
    do {
        assumed = old;
        __half2 h2 = *(__half2*)&assumed;
        float f = (hi ? __high2float(h2) : __low2float(h2)) + val;
        __half2 nh = hi ? __halves2half2(__low2half(h2), __float2half_rn(f))
                        : __halves2half2(__float2half_rn(f), __high2half(h2));
        old = atomicCAS(base, assumed, *(uint32_t*)&nh);
    } while (old != assumed);
}

__global__ __launch_bounds__(256) void k_wfill_all(
        const int* __restrict__ s0, const int* __restrict__ d0, const float* __restrict__ w0,
        const int* __restrict__ s1, const int* __restrict__ d1, const float* __restrict__ w1,
        const int* __restrict__ s2, const int* __restrict__ d2, const float* __restrict__ w2,
        __half* __restrict__ W0d, __half* __restrict__ W1d, __half* __restrict__ W2d) {
    const int e = blockIdx.x * 256 + threadIdx.x;
    if (e < E0)            atomic_add_half(W0d + (size_t)d0[e] * K1 + s0[e], w0[e]);
    else if (e < E0 + E1) { const int i = e - E0;      atomic_add_half(W1d + (size_t)d1[i] * K2 + s1[i], w1[i]); }
    else                  { const int i = e - E0 - E1; atomic_add_half(W2d + (size_t)d2[i] * K3 + s2[i], w2[i]); }
}

__global__ __launch_bounds__(256) void k_wfill01(
        const int* __restrict__ s0, const int* __restrict__ d0, const float* __restrict__ w0,
        const int* __restrict__ s1, const int* __restrict__ d1, const float* __restrict__ w1,
        __half* __restrict__ W0d, __half* __restrict__ W1d) {
    const int e = blockIdx.x * 256 + threadIdx.x;
    if (e < E0)  atomic_add_half(W0d + (size_t)d0[e] * K1 + s0[e], w0[e]);
    else { const int i = e - E0; atomic_add_half(W1d + (size_t)d1[i] * K2 + s1[i], w1[i]); }
}

__global__ __launch_bounds__(256) void k_wfill(const int* __restrict__ src,
                                               const int* __restrict__ dst,
                                               const float* __restrict__ w,
                                               __half* __restrict__ Wd, const int K) {
    const int e = blockIdx.x * 256 + threadIdx.x;
    atomic_add_half(Wd + (size_t)dst[e] * K + src[e], w[e]);
}

// ---------- GEMM levels 1/2: byte-identical to R10 (best measured: 161.4) ----
// BM=96, BN=128, 256 thr, dbuf + counted vmcnt(7); 57.3KB LDS -> 2 blk/CU;
// grid 512 blocks = 2/CU, fully balanced. R11's 8-wave/quad variant regressed
// (cost co-residency, m132 lesson) — do not restructure G1/G2 again.
__global__ __launch_bounds__(256, 2)
void k_gemm96(const __half* __restrict__ A,    // [M][K] dense W, row stride K
              const __half* __restrict__ Bt,   // nvT, row stride NVSTRIDE
              __half* __restrict__ Ch,         // nvT + col0
              const int K) {
    __shared__ __half lA[2][96 * 64];
    __shared__ __half lB[2][128 * 64];
    const int tid  = threadIdx.x;
    const int lane = tid & 63;
    const int wv   = tid >> 6;
    const int wr   = wv >> 1, wc = wv & 1;
    const int m0   = blockIdx.y * 96;
    const int n0   = blockIdx.x * 128;
    const int lrow = lane >> 3;
    const int lchk = lane & 7;

    f32x4 acc[3][4] = {};

#define STAGE96(BUF, KT) {                                                   \
    _Pragma("unroll")                                                        \
    for (int it = 0; it < 3; ++it) {                                         \
        const int row = it * 32 + wv * 8 + lrow;                             \
        const int sc  = lchk ^ (row & 7);                                    \
        GLL(A + (size_t)(m0 + row) * K + (KT) + sc * 8,                      \
            lA[BUF] + (it * 32 + wv * 8) * 64);                              \
    }                                                                        \
    _Pragma("unroll")                                                        \
    for (int it = 0; it < 4; ++it) {                                         \
        const int row = it * 32 + wv * 8 + lrow;                             \
        const int sc  = lchk ^ (row & 7);                                    \
        GLL(Bt + (size_t)(n0 + row) * NVSTRIDE + (KT) + sc * 8,              \
            lB[BUF] + (it * 32 + wv * 8) * 64);                              \
    }                                                                        \
}

    const int NT = K >> 6;
    STAGE96(0, 0)
    int cur = 0;
    for (int t = 0; t < NT; ++t) {
        __builtin_amdgcn_s_barrier();            // prev compute done: safe to overwrite
        __builtin_amdgcn_sched_barrier(0);
        if (t + 1 < NT) {
            STAGE96(cur ^ 1, (t + 1) << 6)
            asm volatile("s_waitcnt vmcnt(7)" ::: "memory");   // t landed, t+1 flies
        } else {
            asm volatile("s_waitcnt vmcnt(0)" ::: "memory");
        }
        __builtin_amdgcn_sched_barrier(0);
        __builtin_amdgcn_s_barrier();            // all waves' tile-t data in LDS
        __builtin_amdgcn_sched_barrier(0);
#pragma unroll
        for (int kk = 0; kk < 2; ++kk) {
            f16x8 af[3], bf[4];
#pragma unroll
            for (int fm = 0; fm < 3; ++fm) {
                const int row = wr * 48 + fm * 16 + (lane & 15);
                const int ch  = (kk * 4 + (lane >> 4)) ^ (row & 7);
                af[fm] = *(const f16x8*)(lA[cur] + row * 64 + ch * 8);
            }
#pragma unroll
            for (int fn = 0; fn < 4; ++fn) {
                const int row = wc * 64 + fn * 16 + (lane & 15);
                const int ch  = (kk * 4 + (lane >> 4)) ^ (row & 7);
                bf[fn] = *(const f16x8*)(lB[cur] + row * 64 + ch * 8);
            }
#pragma unroll
            for (int fm = 0; fm < 3; ++fm)
#pragma unroll
                for (int fn = 0; fn < 4; ++fn)
                    acc[fm][fn] = __builtin_amdgcn_mfma_f32_16x16x32_f16(
                        af[fm], bf[fn], acc[fm][fn], 0, 0, 0);
        }
        cur ^= 1;
    }
#undef STAGE96

    const int cm = (lane >> 4) << 2;
    const int cn = lane & 15;
#pragma unroll
    for (int fm = 0; fm < 3; ++fm)
#pragma unroll
        for (int fn = 0; fn < 4; ++fn) {
            const f32x4 v = acc[fm][fn];
            const __half2 p0 = __floats2half2_rn(fmaxf(v[0], 0.f), fmaxf(v[1], 0.f));
            const __half2 p1 = __floats2half2_rn(fmaxf(v[2], 0.f), fmaxf(v[3], 0.f));
            const int mm = m0 + wr * 48 + fm * 16 + cm;
            const int nn = n0 + wc * 64 + fn * 16 + cn;
            uint2 u; u.x = *(const uint32_t*)&p0; u.y = *(const uint32_t*)&p1;
            *(uint2*)(Ch + (size_t)nn * NVSTRIDE + mm) = u;
        }
}

// ---------- GEMM level 3: R10 structure deepened to depth-3 (5-slot ring) ----
// 512 thr (8 waves, 2x4), BM=64/BN=128, grid 256 = 1 blk/CU — at 1 blk/CU the
// only latency lever is prefetch depth (R10: depth-2 improved 47->~<43).
// Steady state: {STAGE((t+3)%5); vmcnt(9); barrier; compute(t%5)}. Overwrite
// target (t+3)%5 == slot of tile t-2, whose compute finished before barrier
// t-1 — safe. LDS 5*(8+16)KB = 122.9KB (still 1 blk/CU).
__global__ __launch_bounds__(512, 2)
void k_gemm3(const __half* __restrict__ A,     // [512][3584] dense W2
             const __half* __restrict__ Bt,    // nvT
             float* __restrict__ Cf) {         // d_out [4096][512]
    __shared__ __half lA[5][64 * 64];
    __shared__ __half lB[5][128 * 64];
    const int tid  = threadIdx.x;
    const int lane = tid & 63;
    const int wv   = tid >> 6;                  // 0..7
    const int wr   = wv >> 2, wc = wv & 3;      // 2 x 4 wave grid
    const int m0   = blockIdx.y * 64;
    const int n0   = blockIdx.x * 128;
    const int lrow = lane >> 3;
    const int lchk = lane & 7;
    const int K = K3;

    f32x4 acc[2][2] = {};

#define STAGE3(BUF, KT) {                                                    \
    _Pragma("unroll")                                                        \
    for (int i = 0; i < 3; ++i) {                                            \
        const int L = wv * 3 + i;               /* 0..23, wave-uniform */    \
        if (L < 8) {                                                         \
            const int row = L * 8 + lrow;                                    \
            const int sc  = lchk ^ (row & 7);                                \
            GLL(A + (size_t)(m0 + row) * K + (KT) + sc * 8,                  \
                lA[BUF] + L * 512);                                          \
        } else {                                                             \
            const int row = (L - 8) * 8 + lrow;                              \
            const int sc  = lchk ^ (row & 7);                                \
            GLL(Bt + (size_t)(n0 + row) * NVSTRIDE + (KT) + sc * 8,          \
                lB[BUF] + (L - 8) * 512);                                    \
        }                                                                    \
    }                                                                        \
}

    const int NT = K >> 6;   // 56
    STAGE3(0, 0)
    STAGE3(1, 64)
    STAGE3(2, 128)
    int sc_ = 0;                                 // t % 5, maintained incrementally
    int sp3 = 3;                                 // (t+3) % 5
    for (int t = 0; t < NT; ++t) {
        if (t + 3 < NT) {
            STAGE3(sp3, (t + 3) << 6)
            asm volatile("s_waitcnt vmcnt(9)" ::: "memory");   // t landed; t+1..t+3 fly
        } else if (t + 2 < NT) {
            asm volatile("s_waitcnt vmcnt(6)" ::: "memory");
        } else if (t + 1 < NT) {
            asm volatile("s_waitcnt vmcnt(3)" ::: "memory");
        } else {
            asm volatile("s_waitcnt vmcnt(0)" ::: "memory");
        }
        __builtin_amdgcn_sched_barrier(0);
        __builtin_amdgcn_s_barrier();           // all waves' tile-t data in LDS
        __builtin_amdgcn_sched_barrier(0);
        const __half* bA = lA[sc_];
        const __half* bB = lB[sc_];
#pragma unroll
        for (int kk = 0; kk < 2; ++kk) {
            f16x8 af[2], bf[2];
#pragma unroll
            for (int fm = 0; fm < 2; ++fm) {
                const int row = wr * 32 + fm * 16 + (lane & 15);
                const int ch  = (kk * 4 + (lane >> 4)) ^ (row & 7);
                af[fm] = *(const f16x8*)(bA + row * 64 + ch * 8);
            }
#pragma unroll
            for (int fn = 0; fn < 2; ++fn) {
                const int row = wc * 32 + fn * 16 + (lane & 15);
                const int ch  = (kk * 4 + (lane >> 4)) ^ (row & 7);
                bf[fn] = *(const f16x8*)(bB + row * 64 + ch * 8);
            }
#pragma unroll
            for (int fm = 0; fm < 2; ++fm)
#pragma unroll
                for (int fn = 0; fn < 2; ++fn)
                    acc[fm][fn] = __builtin_amdgcn_mfma_f32_16x16x32_f16(
                        af[fm], bf[fn], acc[fm][fn], 0, 0, 0);
        }
        sc_ = (sc_ == 4) ? 0 : sc_ + 1;
        sp3 = (sp3 == 4) ? 0 : sp3 + 1;
    }
#undef STAGE3

    const int cm = (lane >> 4) << 2;
    const int cn = lane & 15;
#pragma unroll
    for (int fm = 0; fm < 2; ++fm)
#pragma unroll
        for (int fn = 0; fn < 2; ++fn) {
            const f32x4 v = acc[fm][fn];
            float4 o;
            o.x = fmaxf(v[0], 0.f); o.y = fmaxf(v[1], 0.f);
            o.z = fmaxf(v[2], 0.f); o.w = fmaxf(v[3], 0.f);
            const int mm = m0 + wr * 32 + fm * 16 + cm;
            const int nn = n0 + wc * 32 + fn * 16 + cn;
            *(float4*)(Cf + (size_t)nn * N_OUT + mm) = o;
        }
}

extern "C" void kernel_launch(void* const* d_in, const int* in_sizes, int n_in,
                              void* d_out, int out_size, void* d_ws, size_t ws_size,
                              hipStream_t stream) {
    const float* x  = (const float*)d_in[0];
    const int* s0   = (const int*)d_in[1];
    const int* dd0  = (const int*)d_in[2];
    const float* w0 = (const float*)d_in[3];
    const int* s1   = (const int*)d_in[4];
    const int* dd1  = (const int*)d_in[5];
    const float* w1 = (const float*)d_in[6];
    const int* s2   = (const int*)d_in[7];
    const int* dd2  = (const int*)d_in[8];
    const float* w2 = (const float*)d_in[9];

    char*   ws  = (char*)d_ws;
    __half* nvT = (__half*)ws;
    __half* W0p = (__half*)(ws + NVBYTES);
    __half* W1p = (__half*)(ws + NVBYTES + W0BYTES);
    float*  out = (float*)d_out;

    if (ws_size >= NVBYTES + W0BYTES + W1BYTES + W2BYTES) {
        // fused 5-dispatch path: separate W2, zero-all in convert kernel,
        // single scatter-fill for all three levels.
        __half* W2p = (__half*)(ws + NVBYTES + W0BYTES + W1BYTES);
        k_xcvt_zero<<<1024 + (WZALLU4 + 255) / 256, 256, 0, stream>>>(
            x, nvT, (uint4*)W0p, (int)WZALLU4);
        k_wfill_all<<<ETOT / 256, 256, 0, stream>>>(s0, dd0, w0, s1, dd1, w1,
                                                    s2, dd2, w2, W0p, W1p, W2p);
        k_gemm96<<<dim3(BATCH / 128, H1 / 96), 256, 0, stream>>>(W0p, nvT, nvT + N_IN, K1);
        k_gemm96<<<dim3(BATCH / 128, H2 / 96), 256, 0, stream>>>(W1p, nvT, nvT + K2, K2);
        k_gemm3<<<dim3(BATCH / 128, N_OUT / 64), 512, 0, stream>>>(W2p, nvT, out);
    } else {
        // fallback: exact R10 sequence (W2 overlays W0/W1; proven 37.2 MB)
        __half* W2p = W0p;
        k_xcvt_zero<<<1024 + (WZ01U4 + 255) / 256, 256, 0, stream>>>(
            x, nvT, (uint4*)W0p, (int)WZ01U4);
        k_wfill01<<<(E0 + E1) / 256, 256, 0, stream>>>(s0, dd0, w0, s1, dd1, w1, W0p, W1p);
        k_gemm96<<<dim3(BATCH / 128, H1 / 96), 256, 0, stream>>>(W0p, nvT, nvT + N_IN, K1);
        k_gemm96<<<dim3(BATCH / 128, H2 / 96), 256, 0, stream>>>(W1p, nvT, nvT + K2, K2);
        hipMemsetAsync(W2p, 0, W2BYTES, stream);
        k_wfill<<<E2 / 256, 256, 0, stream>>>(s2, dd2, w2, W2p, K3);
        k_gemm3<<<dim3(BATCH / 128, N_OUT / 64), 512, 0, stream>>>(W2p, nvT, out);
    }
}

// Round 13
// 143.338 us; speedup vs baseline: 1.1700x; 1.0949x over previous
//
#include <hip/hip_runtime.h>
#include <hip/hip_fp16.h>
#include <stdint.h>

#define BATCH 4096
#define N_IN  512
#define H1    1536
#define H2    1536
#define N_OUT 512
#define FAN   32
#define E0 (H1 * FAN)
#define E1 (H2 * FAN)
#define E2 (N_OUT * FAN)
#define ETOT (E0 + E1 + E2)
#define MAXDEG 128             // slot capacity (Poisson(32), max ~54 measured)
#define NN_TAB (H2 + N_OUT)    // 2048 slotted nodes (L2 + L3)

// ---- workspace layout (bytes), total 37,232,640 (< 37,238,784 proven R0) ----
// nvN   : node-major [4096][4096] fp16 = 33,554,432
//         rows 0..511 x^T | 512..2047 h1 | 2048..3583 h2 | 3584..4095 out^T
// W0    : dense [H1][N_IN] fp16 = 1,572,864           (level-1 GEMM weights)
// cnt   : NN_TAB ints = 8,192                          (slotted-edge counters)
// edges : [NN_TAB][MAXDEG] int2 = 2,097,152            (L2+L3 gather edges)
#define OFF_W0  33554432
#define OFF_CNT (OFF_W0 + 1572864)        // 35,127,296 (W0+cnt contiguous: 1 memset)
#define OFF_EDG (OFF_CNT + NN_TAB * 4)    // 35,135,488

typedef _Float16 f16x8 __attribute__((ext_vector_type(8)));
typedef float    f32x4 __attribute__((ext_vector_type(4)));

#define GLL(SRC, DST)                                                        \
    __builtin_amdgcn_global_load_lds(                                        \
        (const __attribute__((address_space(1))) void*)(const void*)(SRC),   \
        (__attribute__((address_space(3))) void*)(void*)(DST), 16, 0, 0)

// ---------- x [B, N_IN] fp32 -> rows 0..511 of nvN (fp16, [node][batch]) — R0-proven ----------
__global__ __launch_bounds__(256) void k_transpose_in(const float* __restrict__ x,
                                                      __half* __restrict__ xT) {
    __shared__ float tile[32][33];
    const int tx = threadIdx.x, ty = threadIdx.y;   // 32 x 8
    const int n0 = blockIdx.x * 32;
    const int b0 = blockIdx.y * 32;
#pragma unroll
    for (int k = 0; k < 32; k += 8)
        tile[ty + k][tx] = x[(size_t)(b0 + ty + k) * N_IN + (n0 + tx)];
    __syncthreads();
#pragma unroll
    for (int k = 0; k < 32; k += 8)
        xT[(size_t)(n0 + ty + k) * BATCH + (b0 + tx)] = __float2half_rn(tile[tx][ty + k]);
}

// ---------- fp16 scatter-add (CAS; duplicates accumulate) — R8-proven ----------
__device__ __forceinline__ void atomic_add_half(__half* addr, float val) {
    uint32_t* base = (uint32_t*)((size_t)addr & ~(size_t)3);
    const bool hi  = ((size_t)addr & 2) != 0;
    uint32_t old = *base, assumed;
    do {
        assumed = old;
        __half2 h2 = *(__half2*)&assumed;
        float f = (hi ? __high2float(h2) : __low2float(h2)) + val;
        __half2 nh = hi ? __halves2half2(__low2half(h2), __float2half_rn(f))
                        : __halves2half2(__float2half_rn(f), __high2half(h2));
        old = atomicCAS(base, assumed, *(uint32_t*)&nh);
    } while (old != assumed);
}

// ---------- fused build: W0 dense atomics + L2/L3 slotted edge fill ----------
__global__ __launch_bounds__(256) void k_build(
        const int* __restrict__ s0, const int* __restrict__ d0, const float* __restrict__ w0,
        const int* __restrict__ s1, const int* __restrict__ d1, const float* __restrict__ w1,
        const int* __restrict__ s2, const int* __restrict__ d2, const float* __restrict__ w2,
        __half* __restrict__ W0d, int* __restrict__ cnt, int2* __restrict__ edges) {
    const int e = blockIdx.x * 256 + threadIdx.x;
    if (e < E0) {
        atomic_add_half(W0d + (size_t)d0[e] * N_IN + s0[e], w0[e]);
        return;
    }
    int src, node; float w;
    if (e < E0 + E1) { const int i = e - E0;      src = s1[i]; node = d1[i];       w = w1[i]; }
    else             { const int i = e - E0 - E1; src = s2[i]; node = H2 + d2[i];  w = w2[i]; }
    const int pos = atomicAdd(&cnt[node], 1);
    if (pos < MAXDEG) edges[node * MAXDEG + pos] = make_int2(src, __float_as_int(w));
}

// ---------- level-1 GEMM: h1[m][b] = relu(sum_k W0[m][k] x[b][k]) ----------
// BM=96 BN=128 BK=64, 256 thr (2x2 waves), dbuf, counted vmcnt (R10/R12-proven
// schedule). A=W0 via global_load_lds w/ source chunk-XOR (verbatim R12).
// B = x read DIRECTLY as fp32 (batch-major = K-contiguous), reg-staged:
// 8 float4/thread -> cvt fp16 -> swizzled ds_write_b64 (same chunk-XOR
// convention as A, so fragment reads are identical). Issue order: B-loads
// FIRST then A-dma, so vmcnt(3) drains B (8 oldest) while A(t+1) flies.
// Epilogue: node-major scatter store (4 rows x 16 contiguous halfs = 32B
// segments per store inst) into nvN rows 512..2047.
__global__ __launch_bounds__(256, 2)
void k_gemm1(const __half* __restrict__ W0d,   // [H1][512]
             const float* __restrict__ x,      // [4096][512] fp32
             __half* __restrict__ nvh) {       // nvN base (halfs)
    __shared__ __half lA[2][96 * 64];
    __shared__ __half lB[2][128 * 64];
    const int tid  = threadIdx.x;
    const int lane = tid & 63;
    const int wv   = tid >> 6;
    const int wr   = wv >> 1, wc = wv & 1;
    const int m0   = blockIdx.y * 96;
    const int n0   = blockIdx.x * 128;
    const int lrow = lane >> 3;
    const int lchk = lane & 7;
    const int brow = tid >> 4;       // B-stage: row-in-16-group
    const int bl16 = tid & 15;       // B-stage: 16 lanes cover 64 k (4 fp32 each)

    f32x4 acc[3][4] = {};
    float4 breg[8];

#define ADMA(BUF, KT) {                                                      \
    _Pragma("unroll")                                                        \
    for (int it = 0; it < 3; ++it) {                                         \
        const int row = it * 32 + wv * 8 + lrow;                             \
        const int sc  = lchk ^ (row & 7);                                    \
        GLL(W0d + (size_t)(m0 + row) * N_IN + (KT) + sc * 8,                 \
            lA[BUF] + (it * 32 + wv * 8) * 64);                              \
    }                                                                        \
}
#define BLOAD(KT) {                                                          \
    _Pragma("unroll")                                                        \
    for (int it = 0; it < 8; ++it) {                                         \
        const int r = it * 16 + brow;                                        \
        breg[it] = *(const float4*)(x + (size_t)(n0 + r) * N_IN + (KT) + bl16 * 4); \
    }                                                                        \
}
#define BWRITE(BUF) {                                                        \
    _Pragma("unroll")                                                        \
    for (int it = 0; it < 8; ++it) {                                         \
        const int r    = it * 16 + brow;                                     \
        const int byte = r * 128 + (((bl16 >> 1) ^ (r & 7)) * 16) + ((bl16 & 1) * 8); \
        const __half2 h01 = __floats2half2_rn(breg[it].x, breg[it].y);       \
        const __half2 h23 = __floats2half2_rn(breg[it].z, breg[it].w);       \
        uint2 u; u.x = *(const uint32_t*)&h01; u.y = *(const uint32_t*)&h23; \
        *(uint2*)((char*)&lB[BUF][0] + byte) = u;                            \
    }                                                                        \
}

    const int NT = N_IN >> 6;   // 8
    // prologue: B loads first (oldest), then A dma; vmcnt(3) = B done, A flying
    BLOAD(0)
    ADMA(0, 0)
    asm volatile("s_waitcnt vmcnt(3)" ::: "memory");
    __builtin_amdgcn_sched_barrier(0);
    BWRITE(0)

    int cur = 0;
    for (int t = 0; t < NT; ++t) {
        __builtin_amdgcn_s_barrier();            // prev compute done: overwrite safe
        __builtin_amdgcn_sched_barrier(0);
        if (t + 1 < NT) {
            BLOAD((t + 1) << 6)
            ADMA(cur ^ 1, (t + 1) << 6)
            asm volatile("s_waitcnt vmcnt(3)" ::: "memory");  // B(t+1)+A(t) done; A(t+1) flies
            __builtin_amdgcn_sched_barrier(0);
            BWRITE(cur ^ 1)
        } else {
            asm volatile("s_waitcnt vmcnt(0)" ::: "memory");
        }
        asm volatile("s_waitcnt lgkmcnt(0)" ::: "memory");    // own ds_writes committed
        __builtin_amdgcn_sched_barrier(0);
        __builtin_amdgcn_s_barrier();            // all waves' tile-t data visible
        __builtin_amdgcn_sched_barrier(0);
#pragma unroll
        for (int kk = 0; kk < 2; ++kk) {
            f16x8 af[3], bf[4];
#pragma unroll
            for (int fm = 0; fm < 3; ++fm) {
                const int row = wr * 48 + fm * 16 + (lane & 15);
                const int ch  = (kk * 4 + (lane >> 4)) ^ (row & 7);
                af[fm] = *(const f16x8*)(lA[cur] + row * 64 + ch * 8);
            }
#pragma unroll
            for (int fn = 0; fn < 4; ++fn) {
                const int row = wc * 64 + fn * 16 + (lane & 15);
                const int ch  = (kk * 4 + (lane >> 4)) ^ (row & 7);
                bf[fn] = *(const f16x8*)(lB[cur] + row * 64 + ch * 8);
            }
#pragma unroll
            for (int fm = 0; fm < 3; ++fm)
#pragma unroll
                for (int fn = 0; fn < 4; ++fn)
                    acc[fm][fn] = __builtin_amdgcn_mfma_f32_16x16x32_f16(
                        af[fm], bf[fn], acc[fm][fn], 0, 0, 0);
        }
        cur ^= 1;
    }
#undef BWRITE
#undef BLOAD
#undef ADMA

    // epilogue: relu + node-major store. D map: col=lane&15 (batch), row=(lane>>4)*4+j (node)
    const int cm = (lane >> 4) << 2;
    const int cn = lane & 15;
#pragma unroll
    for (int fm = 0; fm < 3; ++fm)
#pragma unroll
        for (int fn = 0; fn < 4; ++fn) {
            const f32x4 v = acc[fm][fn];
            const int mm = m0 + wr * 48 + fm * 16 + cm;   // h1 node index
            const int nn = n0 + wc * 64 + fn * 16 + cn;   // batch index
#pragma unroll
            for (int j = 0; j < 4; ++j)
                nvh[(size_t)(N_IN + mm + j) * BATCH + nn] =
                    __float2half_rn(fmaxf(v[j], 0.f));
        }
}

// ---------- gather level kernel — byte-identical to R2 (proven 147.6 base) ----------
__global__ __launch_bounds__(256, 8)
void k_level(const int2* __restrict__ edges,   // pre-offset: table base * MAXDEG
             const int* __restrict__ cnt,      // pre-offset: table node base
             const uint4* __restrict__ nv,     // 512 uint4 per node row (fp16 x8)
             uint4* __restrict__ outb) {       // pre-offset row base (uint4 units)
    const int lane = threadIdx.x & 63;
    const int wv   = threadIdx.x >> 6;
    const int node = __builtin_amdgcn_readfirstlane((blockIdx.y << 2) | wv);
    const int col8 = (blockIdx.x << 6) | lane;  // uint4 index in row, 0..511

    int c = cnt[node];
    c = (c < 0) ? 0 : (c > MAXDEG ? MAXDEG : c);

    float a0 = 0.f, a1 = 0.f, a2 = 0.f, a3 = 0.f, a4 = 0.f, a5 = 0.f, a6 = 0.f, a7 = 0.f;

#define ACC8(q, W) {                                                    \
    const __half2 h0 = *(const __half2*)&(q).x;                         \
    const __half2 h1 = *(const __half2*)&(q).y;                         \
    const __half2 h2 = *(const __half2*)&(q).z;                         \
    const __half2 h3 = *(const __half2*)&(q).w;                         \
    a0 = fmaf(__low2float(h0),  (W), a0);                               \
    a1 = fmaf(__high2float(h0), (W), a1);                               \
    a2 = fmaf(__low2float(h1),  (W), a2);                               \
    a3 = fmaf(__high2float(h1), (W), a3);                               \
    a4 = fmaf(__low2float(h2),  (W), a4);                               \
    a5 = fmaf(__high2float(h2), (W), a5);                               \
    a6 = fmaf(__low2float(h3),  (W), a6);                               \
    a7 = fmaf(__high2float(h3), (W), a7); }

    for (int base = 0; base < c; base += 64) {
        const int2 my = edges[(size_t)node * MAXDEG + base + lane];
        const int m = (c - base < 64) ? (c - base) : 64;
        int j = 0;
        for (; j + 4 <= m; j += 4) {
            const int   s0i = __builtin_amdgcn_readlane(my.x, j)     & 4095;
            const int   s1i = __builtin_amdgcn_readlane(my.x, j + 1) & 4095;
            const int   s2i = __builtin_amdgcn_readlane(my.x, j + 2) & 4095;
            const int   s3i = __builtin_amdgcn_readlane(my.x, j + 3) & 4095;
            const float wa  = __int_as_float(__builtin_amdgcn_readlane(my.y, j));
            const float wb  = __int_as_float(__builtin_amdgcn_readlane(my.y, j + 1));
            const float wc_ = __int_as_float(__builtin_amdgcn_readlane(my.y, j + 2));
            const float wd  = __int_as_float(__builtin_amdgcn_readlane(my.y, j + 3));
            const uint4 q0 = nv[((size_t)s0i << 9) | col8];
            const uint4 q1 = nv[((size_t)s1i << 9) | col8];
            const uint4 q2 = nv[((size_t)s2i << 9) | col8];
            const uint4 q3 = nv[((size_t)s3i << 9) | col8];
            ACC8(q0, wa);
            ACC8(q1, wb);
            ACC8(q2, wc_);
            ACC8(q3, wd);
        }
        for (; j < m; ++j) {
            const int   s0i = __builtin_amdgcn_readlane(my.x, j) & 4095;
            const float wa  = __int_as_float(__builtin_amdgcn_readlane(my.y, j));
            const uint4 q0 = nv[((size_t)s0i << 9) | col8];
            ACC8(q0, wa);
        }
    }
#undef ACC8

    a0 = fmaxf(a0, 0.f); a1 = fmaxf(a1, 0.f); a2 = fmaxf(a2, 0.f); a3 = fmaxf(a3, 0.f);
    a4 = fmaxf(a4, 0.f); a5 = fmaxf(a5, 0.f); a6 = fmaxf(a6, 0.f); a7 = fmaxf(a7, 0.f);

    const __half2 h0 = __floats2half2_rn(a0, a1);
    const __half2 h1 = __floats2half2_rn(a2, a3);
    const __half2 h2 = __floats2half2_rn(a4, a5);
    const __half2 h3 = __floats2half2_rn(a6, a7);
    uint4 p;
    p.x = *(const uint32_t*)&h0; p.y = *(const uint32_t*)&h1;
    p.z = *(const uint32_t*)&h2; p.w = *(const uint32_t*)&h3;
    outb[((size_t)node << 9) | col8] = p;
}

// ---------- out^T rows (fp16, [N_OUT][B]) -> d_out [B, N_OUT] fp32 — R0-proven ----------
__global__ __launch_bounds__(256) void k_transpose_out(const __half* __restrict__ outh,
                                                       float* __restrict__ out) {
    __shared__ float tile[32][33];
    const int tx = threadIdx.x, ty = threadIdx.y;   // 32 x 8
    const int n0 = blockIdx.x * 32;
    const int b0 = blockIdx.y * 32;
#pragma unroll
    for (int k = 0; k < 32; k += 8)
        tile[ty + k][tx] = __half2float(outh[(size_t)(n0 + ty + k) * BATCH + (b0 + tx)]);
    __syncthreads();
#pragma unroll
    for (int k = 0; k < 32; k += 8)
        out[(size_t)(b0 + ty + k) * N_OUT + (n0 + tx)] = tile[tx][ty + k];
}

extern "C" void kernel_launch(void* const* d_in, const int* in_sizes, int n_in,
                              void* d_out, int out_size, void* d_ws, size_t ws_size,
                              hipStream_t stream) {
    const float* x  = (const float*)d_in[0];
    const int* s0   = (const int*)d_in[1];
    const int* dd0  = (const int*)d_in[2];
    const float* w0 = (const float*)d_in[3];
    const int* s1   = (const int*)d_in[4];
    const int* dd1  = (const int*)d_in[5];
    const float* w1 = (const float*)d_in[6];
    const int* s2   = (const int*)d_in[7];
    const int* dd2  = (const int*)d_in[8];
    const float* w2 = (const float*)d_in[9];

    char*     ws    = (char*)d_ws;
    __half*   nvh   = (__half*)ws;                   // node-major fp16 rows
    uint4*    nv4   = (uint4*)ws;
    __half*   W0p   = (__half*)(ws + OFF_W0);
    int*      cnt   = (int*)(ws + OFF_CNT);
    int2*     edges = (int2*)(ws + OFF_EDG);

    // zero W0 + cnt (contiguous region, one memset)
    hipMemsetAsync(W0p, 0, (size_t)1572864 + NN_TAB * 4, stream);

    // x -> node-major rows 0..511 (needed by the L2 gather)
    k_transpose_in<<<dim3(N_IN / 32, BATCH / 32), dim3(32, 8), 0, stream>>>(x, nvh);

    // one fused build: W0 dense atomics + L2/L3 slotted edges
    k_build<<<ETOT / 256, 256, 0, stream>>>(s0, dd0, w0, s1, dd1, w1, s2, dd2, w2,
                                            W0p, cnt, edges);

    // level 1 = GEMM (B = x fp32 direct), output node-major rows 512..2047
    k_gemm1<<<dim3(BATCH / 128, H1 / 96), 256, 0, stream>>>(W0p, x, nvh);

    // level 2 = gather (table nodes 0..1535), output rows 2048..3583
    k_level<<<dim3(8, H2 / 4), 256, 0, stream>>>(edges, cnt, nv4,
                                                 nv4 + (size_t)(N_IN + H1) * 512);

    // level 3 = gather (table nodes 1536..2047), output rows 3584..4095
    k_level<<<dim3(8, N_OUT / 4), 256, 0, stream>>>(edges + (size_t)H2 * MAXDEG, cnt + H2,
                                                    nv4, nv4 + (size_t)(N_IN + H1 + H2) * 512);

    // out^T -> d_out [B, N_OUT] fp32
    k_transpose_out<<<dim3(N_OUT / 32, BATCH / 32), dim3(32, 8), 0, stream>>>(
        (const __half*)(ws + (size_t)(N_IN + H1 + H2) * BATCH * 2), (float*)d_out);
}

// Round 14
// 139.801 us; speedup vs baseline: 1.1996x; 1.0253x over previous
//
#include <hip/hip_runtime.h>
#include <hip/hip_fp16.h>
#include <stdint.h>

#define BATCH 4096
#define N_IN  512
#define H1    1536
#define H2    1536
#define N_OUT 512
#define FAN   32
#define E0 (H1 * FAN)
#define E1 (H2 * FAN)
#define E2 (N_OUT * FAN)
#define ETOT (E0 + E1 + E2)
#define EBLK (ETOT / 256)      // 448 build blocks
#define MAXDEG 128             // slot capacity (Poisson(32), max ~54 measured)
#define NN_TAB (H2 + N_OUT)    // 2048 slotted nodes (L2 + L3)

// ---- workspace layout (bytes), total 37,232,640 (< 37,238,784 proven R0) ----
// nvN   : node-major [4096][4096] fp16 = 33,554,432
//         rows 0..511 x^T | 512..2047 h1 | 2048..3583 h2 | 3584..4095 out^T
// W0    : dense [H1][N_IN] fp16 = 1,572,864           (level-1 GEMM weights)
// cnt   : NN_TAB ints = 8,192                          (slotted-edge counters)
// edges : [NN_TAB][MAXDEG] int2 = 2,097,152            (L2+L3 gather edges)
#define OFF_W0  33554432
#define OFF_CNT (OFF_W0 + 1572864)        // 35,127,296 (W0+cnt contiguous: 1 memset)
#define OFF_EDG (OFF_CNT + NN_TAB * 4)    // 35,135,488

typedef _Float16 f16x8 __attribute__((ext_vector_type(8)));
typedef float    f32x4 __attribute__((ext_vector_type(4)));

#define GLL(SRC, DST)                                                        \
    __builtin_amdgcn_global_load_lds(                                        \
        (const __attribute__((address_space(1))) void*)(const void*)(SRC),   \
        (__attribute__((address_space(3))) void*)(void*)(DST), 16, 0, 0)

// ---------- fp16 scatter-add (CAS; duplicates accumulate) — R8-proven ----------
__device__ __forceinline__ void atomic_add_half(__half* addr, float val) {
    uint32_t* base = (uint32_t*)((size_t)addr & ~(size_t)3);
    const bool hi  = ((size_t)addr & 2) != 0;
    uint32_t old = *base, assumed;
    do {
        assumed = old;
        __half2 h2 = *(__half2*)&assumed;
        float f = (hi ? __high2float(h2) : __low2float(h2)) + val;
        __half2 nh = hi ? __halves2half2(__low2half(h2), __float2half_rn(f))
                        : __halves2half2(__float2half_rn(f), __high2half(h2));
        old = atomicCAS(base, assumed, *(uint32_t*)&nh);
    } while (old != assumed);
}

// ---------- fused: {W0 atomics + L2/L3 edge fill} ∥ {x -> x^T node-major} ----------
// Blocks 0..447: edge/W0 build (R13-proven bodies). Blocks 448..2495: 32x32
// transpose tiles. Disjoint outputs, no ordering needed within the dispatch.
// Transpose batch-tile mapping is XCD-swizzled so the batch slice [c*512,+512)
// lands on XCD c ((448+t)%8 == t%8) — matching the L2 gather's col-tile c
// reader (producer-L2 = consumer-L2).
__global__ __launch_bounds__(256) void k_build(
        const int* __restrict__ s0, const int* __restrict__ d0, const float* __restrict__ w0,
        const int* __restrict__ s1, const int* __restrict__ d1, const float* __restrict__ w1,
        const int* __restrict__ s2, const int* __restrict__ d2, const float* __restrict__ w2,
        __half* __restrict__ W0d, int* __restrict__ cnt, int2* __restrict__ edges,
        const float* __restrict__ x, __half* __restrict__ xT) {
    __shared__ float tile[32][33];
    const int b   = blockIdx.x;
    const int tid = threadIdx.x;
    if (b < EBLK) {
        const int e = b * 256 + tid;
        if (e < E0) {
            atomic_add_half(W0d + (size_t)d0[e] * N_IN + s0[e], w0[e]);
            return;
        }
        int src, node; float w;
        if (e < E0 + E1) { const int i = e - E0;      src = s1[i]; node = d1[i];       w = w1[i]; }
        else             { const int i = e - E0 - E1; src = s2[i]; node = H2 + d2[i];  w = w2[i]; }
        const int pos = atomicAdd(&cnt[node], 1);
        if (pos < MAXDEG) edges[node * MAXDEG + pos] = make_int2(src, __float_as_int(w));
        return;
    }
    // transpose tile t: bb = batch-tile (XCD-swizzled), nt = node-tile
    const int t  = b - EBLK;                    // 0..2047
    const int bb = (t & 7) * 16 + ((t >> 3) & 15);
    const int nt = t >> 7;
    const int n0 = nt * 32;
    const int b0 = bb * 32;
    const int tx = tid & 31, ty = tid >> 5;     // 32 x 8
#pragma unroll
    for (int k = 0; k < 32; k += 8)
        tile[ty + k][tx] = x[(size_t)(b0 + ty + k) * N_IN + (n0 + tx)];
    __syncthreads();
#pragma unroll
    for (int k = 0; k < 32; k += 8)
        xT[(size_t)(n0 + ty + k) * BATCH + (b0 + tx)] = __float2half_rn(tile[tx][ty + k]);
}

// ---------- level-1 GEMM: h1[m][b] = relu(sum_k W0[m][k] x[b][k]) ----------
// R13-proven structure (BM=96 BN=128 BK=64, 256 thr, dbuf, counted vmcnt,
// A=W0 GLL chunk-XOR, B=x fp32 reg-staged + swizzled ds_write, node-major
// scatter epilogue). R14 delta: batch-tile XCD-swizzle (bt = (bx%8)*4 + bx/8)
// so the h1 rows this block writes for batch slice [k*512,+512) are produced
// on XCD k = the XCD that re-reads them in the L2 gather.
__global__ __launch_bounds__(256, 2)
void k_gemm1(const __half* __restrict__ W0d,   // [H1][512]
             const float* __restrict__ x,      // [4096][512] fp32
             __half* __restrict__ nvh) {       // nvN base (halfs)
    __shared__ __half lA[2][96 * 64];
    __shared__ __half lB[2][128 * 64];
    const int tid  = threadIdx.x;
    const int lane = tid & 63;
    const int wv   = tid >> 6;
    const int wr   = wv >> 1, wc = wv & 1;
    const int m0   = blockIdx.y * 96;
    const int bx   = blockIdx.x;
    const int bt   = (bx & 7) * 4 + (bx >> 3);  // XCD-matched batch-tile
    const int n0   = bt * 128;
    const int lrow = lane >> 3;
    const int lchk = lane & 7;
    const int brow = tid >> 4;       // B-stage: row-in-16-group
    const int bl16 = tid & 15;       // B-stage: 16 lanes cover 64 k (4 fp32 each)

    f32x4 acc[3][4] = {};
    float4 breg[8];

#define ADMA(BUF, KT) {                                                      \
    _Pragma("unroll")                                                        \
    for (int it = 0; it < 3; ++it) {                                         \
        const int row = it * 32 + wv * 8 + lrow;                             \
        const int sc  = lchk ^ (row & 7);                                    \
        GLL(W0d + (size_t)(m0 + row) * N_IN + (KT) + sc * 8,                 \
            lA[BUF] + (it * 32 + wv * 8) * 64);                              \
    }                                                                        \
}
#define BLOAD(KT) {                                                          \
    _Pragma("unroll")                                                        \
    for (int it = 0; it < 8; ++it) {                                         \
        const int r = it * 16 + brow;                                        \
        breg[it] = *(const float4*)(x + (size_t)(n0 + r) * N_IN + (KT) + bl16 * 4); \
    }                                                                        \
}
#define BWRITE(BUF) {                                                        \
    _Pragma("unroll")                                                        \
    for (int it = 0; it < 8; ++it) {                                         \
        const int r    = it * 16 + brow;                                     \
        const int byte = r * 128 + (((bl16 >> 1) ^ (r & 7)) * 16) + ((bl16 & 1) * 8); \
        const __half2 h01 = __floats2half2_rn(breg[it].x, breg[it].y);       \
        const __half2 h23 = __floats2half2_rn(breg[it].z, breg[it].w);       \
        uint2 u; u.x = *(const uint32_t*)&h01; u.y = *(const uint32_t*)&h23; \
        *(uint2*)((char*)&lB[BUF][0] + byte) = u;                            \
    }                                                                        \
}

    const int NT = N_IN >> 6;   // 8
    BLOAD(0)
    ADMA(0, 0)
    asm volatile("s_waitcnt vmcnt(3)" ::: "memory");
    __builtin_amdgcn_sched_barrier(0);
    BWRITE(0)

    int cur = 0;
    for (int t = 0; t < NT; ++t) {
        __builtin_amdgcn_s_barrier();            // prev compute done: overwrite safe
        __builtin_amdgcn_sched_barrier(0);
        if (t + 1 < NT) {
            BLOAD((t + 1) << 6)
            ADMA(cur ^ 1, (t + 1) << 6)
            asm volatile("s_waitcnt vmcnt(3)" ::: "memory");  // B(t+1)+A(t) done; A(t+1) flies
            __builtin_amdgcn_sched_barrier(0);
            BWRITE(cur ^ 1)
        } else {
            asm volatile("s_waitcnt vmcnt(0)" ::: "memory");
        }
        asm volatile("s_waitcnt lgkmcnt(0)" ::: "memory");    // own ds_writes committed
        __builtin_amdgcn_sched_barrier(0);
        __builtin_amdgcn_s_barrier();            // all waves' tile-t data visible
        __builtin_amdgcn_sched_barrier(0);
#pragma unroll
        for (int kk = 0; kk < 2; ++kk) {
            f16x8 af[3], bf[4];
#pragma unroll
            for (int fm = 0; fm < 3; ++fm) {
                const int row = wr * 48 + fm * 16 + (lane & 15);
                const int ch  = (kk * 4 + (lane >> 4)) ^ (row & 7);
                af[fm] = *(const f16x8*)(lA[cur] + row * 64 + ch * 8);
            }
#pragma unroll
            for (int fn = 0; fn < 4; ++fn) {
                const int row = wc * 64 + fn * 16 + (lane & 15);
                const int ch  = (kk * 4 + (lane >> 4)) ^ (row & 7);
                bf[fn] = *(const f16x8*)(lB[cur] + row * 64 + ch * 8);
            }
#pragma unroll
            for (int fm = 0; fm < 3; ++fm)
#pragma unroll
                for (int fn = 0; fn < 4; ++fn)
                    acc[fm][fn] = __builtin_amdgcn_mfma_f32_16x16x32_f16(
                        af[fm], bf[fn], acc[fm][fn], 0, 0, 0);
        }
        cur ^= 1;
    }
#undef BWRITE
#undef BLOAD
#undef ADMA

    // epilogue: relu + node-major store. D map: col=lane&15 (batch), row=(lane>>4)*4+j (node)
    const int cm = (lane >> 4) << 2;
    const int cn = lane & 15;
#pragma unroll
    for (int fm = 0; fm < 3; ++fm)
#pragma unroll
        for (int fn = 0; fn < 4; ++fn) {
            const f32x4 v = acc[fm][fn];
            const int mm = m0 + wr * 48 + fm * 16 + cm;   // h1 node index
            const int nn = n0 + wc * 64 + fn * 16 + cn;   // batch index
#pragma unroll
            for (int j = 0; j < 4; ++j)
                nvh[(size_t)(N_IN + mm + j) * BATCH + nn] =
                    __float2half_rn(fmaxf(v[j], 0.f));
        }
}

// ---------- gather level kernel — byte-identical to R2 (proven base) ----------
__global__ __launch_bounds__(256, 8)
void k_level(const int2* __restrict__ edges,   // pre-offset: table base * MAXDEG
             const int* __restrict__ cnt,      // pre-offset: table node base
             const uint4* __restrict__ nv,     // 512 uint4 per node row (fp16 x8)
             uint4* __restrict__ outb) {       // pre-offset row base (uint4 units)
    const int lane = threadIdx.x & 63;
    const int wv   = threadIdx.x >> 6;
    const int node = __builtin_amdgcn_readfirstlane((blockIdx.y << 2) | wv);
    const int col8 = (blockIdx.x << 6) | lane;  // uint4 index in row, 0..511

    int c = cnt[node];
    c = (c < 0) ? 0 : (c > MAXDEG ? MAXDEG : c);

    float a0 = 0.f, a1 = 0.f, a2 = 0.f, a3 = 0.f, a4 = 0.f, a5 = 0.f, a6 = 0.f, a7 = 0.f;

#define ACC8(q, W) {                                                    \
    const __half2 h0 = *(const __half2*)&(q).x;                         \
    const __half2 h1 = *(const __half2*)&(q).y;                         \
    const __half2 h2 = *(const __half2*)&(q).z;                         \
    const __half2 h3 = *(const __half2*)&(q).w;                         \
    a0 = fmaf(__low2float(h0),  (W), a0);                               \
    a1 = fmaf(__high2float(h0), (W), a1);                               \
    a2 = fmaf(__low2float(h1),  (W), a2);                               \
    a3 = fmaf(__high2float(h1), (W), a3);                               \
    a4 = fmaf(__low2float(h2),  (W), a4);                               \
    a5 = fmaf(__high2float(h2), (W), a5);                               \
    a6 = fmaf(__low2float(h3),  (W), a6);                               \
    a7 = fmaf(__high2float(h3), (W), a7); }

    for (int base = 0; base < c; base += 64) {
        const int2 my = edges[(size_t)node * MAXDEG + base + lane];
        const int m = (c - base < 64) ? (c - base) : 64;
        int j = 0;
        for (; j + 4 <= m; j += 4) {
            const int   s0i = __builtin_amdgcn_readlane(my.x, j)     & 4095;
            const int   s1i = __builtin_amdgcn_readlane(my.x, j + 1) & 4095;
            const int   s2i = __builtin_amdgcn_readlane(my.x, j + 2) & 4095;
            const int   s3i = __builtin_amdgcn_readlane(my.x, j + 3) & 4095;
            const float wa  = __int_as_float(__builtin_amdgcn_readlane(my.y, j));
            const float wb  = __int_as_float(__builtin_amdgcn_readlane(my.y, j + 1));
            const float wc_ = __int_as_float(__builtin_amdgcn_readlane(my.y, j + 2));
            const float wd  = __int_as_float(__builtin_amdgcn_readlane(my.y, j + 3));
            const uint4 q0 = nv[((size_t)s0i << 9) | col8];
            const uint4 q1 = nv[((size_t)s1i << 9) | col8];
            const uint4 q2 = nv[((size_t)s2i << 9) | col8];
            const uint4 q3 = nv[((size_t)s3i << 9) | col8];
            ACC8(q0, wa);
            ACC8(q1, wb);
            ACC8(q2, wc_);
            ACC8(q3, wd);
        }
        for (; j < m; ++j) {
            const int   s0i = __builtin_amdgcn_readlane(my.x, j) & 4095;
            const float wa  = __int_as_float(__builtin_amdgcn_readlane(my.y, j));
            const uint4 q0 = nv[((size_t)s0i << 9) | col8];
            ACC8(q0, wa);
        }
    }
#undef ACC8

    a0 = fmaxf(a0, 0.f); a1 = fmaxf(a1, 0.f); a2 = fmaxf(a2, 0.f); a3 = fmaxf(a3, 0.f);
    a4 = fmaxf(a4, 0.f); a5 = fmaxf(a5, 0.f); a6 = fmaxf(a6, 0.f); a7 = fmaxf(a7, 0.f);

    const __half2 h0 = __floats2half2_rn(a0, a1);
    const __half2 h1 = __floats2half2_rn(a2, a3);
    const __half2 h2 = __floats2half2_rn(a4, a5);
    const __half2 h3 = __floats2half2_rn(a6, a7);
    uint4 p;
    p.x = *(const uint32_t*)&h0; p.y = *(const uint32_t*)&h1;
    p.z = *(const uint32_t*)&h2; p.w = *(const uint32_t*)&h3;
    outb[((size_t)node << 9) | col8] = p;
}

// ---------- out^T rows (fp16, [N_OUT][B]) -> d_out [B, N_OUT] fp32 — R0-proven ----------
__global__ __launch_bounds__(256) void k_transpose_out(const __half* __restrict__ outh,
                                                       float* __restrict__ out) {
    __shared__ float tile[32][33];
    const int tx = threadIdx.x, ty = threadIdx.y;   // 32 x 8
    const int n0 = blockIdx.x * 32;
    const int b0 = blockIdx.y * 32;
#pragma unroll
    for (int k = 0; k < 32; k += 8)
        tile[ty + k][tx] = __half2float(outh[(size_t)(n0 + ty + k) * BATCH + (b0 + tx)]);
    __syncthreads();
#pragma unroll
    for (int k = 0; k < 32; k += 8)
        out[(size_t)(b0 + ty + k) * N_OUT + (n0 + tx)] = tile[tx][ty + k];
}

extern "C" void kernel_launch(void* const* d_in, const int* in_sizes, int n_in,
                              void* d_out, int out_size, void* d_ws, size_t ws_size,
                              hipStream_t stream) {
    const float* x  = (const float*)d_in[0];
    const int* s0   = (const int*)d_in[1];
    const int* dd0  = (const int*)d_in[2];
    const float* w0 = (const float*)d_in[3];
    const int* s1   = (const int*)d_in[4];
    const int* dd1  = (const int*)d_in[5];
    const float* w1 = (const float*)d_in[6];
    const int* s2   = (const int*)d_in[7];
    const int* dd2  = (const int*)d_in[8];
    const float* w2 = (const float*)d_in[9];

    char*     ws    = (char*)d_ws;
    __half*   nvh   = (__half*)ws;                   // node-major fp16 rows
    uint4*    nv4   = (uint4*)ws;
    __half*   W0p   = (__half*)(ws + OFF_W0);
    int*      cnt   = (int*)(ws + OFF_CNT);
    int2*     edges = (int2*)(ws + OFF_EDG);

    // zero W0 + cnt (contiguous region, one memset)
    hipMemsetAsync(W0p, 0, (size_t)1572864 + NN_TAB * 4, stream);

    // fused build: {W0 atomics + L2/L3 edges} || {x -> x^T node-major}
    k_build<<<EBLK + 2048, 256, 0, stream>>>(s0, dd0, w0, s1, dd1, w1, s2, dd2, w2,
                                             W0p, cnt, edges, x, nvh);

    // level 1 = GEMM (B = x fp32 direct), output node-major rows 512..2047
    k_gemm1<<<dim3(BATCH / 128, H1 / 96), 256, 0, stream>>>(W0p, x, nvh);

    // level 2 = gather (table nodes 0..1535), output rows 2048..3583
    k_level<<<dim3(8, H2 / 4), 256, 0, stream>>>(edges, cnt, nv4,
                                                 nv4 + (size_t)(N_IN + H1) * 512);

    // level 3 = gather (table nodes 1536..2047), output rows 3584..4095
    k_level<<<dim3(8, N_OUT / 4), 256, 0, stream>>>(edges + (size_t)H2 * MAXDEG, cnt + H2,
                                                    nv4, nv4 + (size_t)(N_IN + H1 + H2) * 512);

    // out^T -> d_out [B, N_OUT] fp32
    k_transpose_out<<<dim3(N_OUT / 32, BATCH / 32), dim3(32, 8), 0, stream>>>(
        (const __half*)(ws + (size_t)(N_IN + H1 + H2) * BATCH * 2), (float*)d_out);
}